// Round 10
// baseline (380.830 us; speedup 1.0000x reference)
//
#include <hip/hip_runtime.h>
#include <hip/hip_bf16.h>

// 3-layer GCN. Round 10: compressed build chain.
//   build1 (one kernel): bincount8 grid-stride + last-block-does-scan
//                        (decoupled via done-counter) + convw in extra blocks
//   bin_scatter: dst cached in LDS (pass B reads only src)
//   bucket_place: segment staged in LDS once (fallback to global if >4096)
//   GEMM epilogue: Hs = (X@W)*dinv[row] (bf16)
//   gather: A = relu(di*(sum Hs[s] + Hs[d]) + b)  bf16  (8-deep MLP, no LDS)
//   final_mfma: logits = Ba@Wout + bout (MFMA) ; log_softmax via shfl_xor
// Requires N <= 131072 (NB <= 1024) and N < 2^25 for packing.

#define FEAT 128
#define OUTF 64
#define BSH 7                 // 128 nodes per bucket
#define BNODES (1 << BSH)
#define SCHUNK_SH 12          // 4096 edges per bin_scatter block
#define SCHUNK (1 << SCHUNK_SH)
#define NREP 8                // cursor replicas per bucket
#define NHIST 256             // histogram blocks in build1

typedef __attribute__((ext_vector_type(8))) short short8;
typedef __attribute__((ext_vector_type(4))) float f32x4;

__device__ __forceinline__ unsigned short bf16_rn(float f) {
    unsigned int u = __float_as_uint(f);
    u += 0x7FFFu + ((u >> 16) & 1u);   // round-to-nearest-even
    return (unsigned short)(u >> 16);
}
__device__ __forceinline__ float bf16_lo(unsigned int u) { return __uint_as_float(u << 16); }
__device__ __forceinline__ float bf16_hi(unsigned int u) { return __uint_as_float(u & 0xFFFF0000u); }

// ---- build1: [blocks 0..NHIST) histogram + last-block scan; rest convw ----
__global__ __launch_bounds__(256) void build1_kernel(
        const int* __restrict__ dst, int* __restrict__ bcnt8,
        int* __restrict__ done, int* __restrict__ bcur8, int* __restrict__ bbase,
        int E, int NB,
        const float* __restrict__ W1, const float* __restrict__ W2,
        const float* __restrict__ Wout,
        __hip_bfloat16* __restrict__ W1t, __hip_bfloat16* __restrict__ W2t,
        __hip_bfloat16* __restrict__ WoutT) {
    int t = threadIdx.x;
    int bid = blockIdx.x;

    if (bid >= NHIST) {
        // ---- weight conversion ----
        int idx = (bid - NHIST) * 256 + t;
        if (idx < 2 * FEAT * FEAT) {
            int which = idx >> 14;
            int r = idx & (FEAT * FEAT - 1);
            int n = r >> 7, k = r & 127;
            const float* W = which ? W2 : W1;
            unsigned short* Wt = (unsigned short*)(which ? W2t : W1t);
            Wt[r] = bf16_rn(W[k * FEAT + n]);
        } else if (idx < 2 * FEAT * FEAT + OUTF * FEAT) {
            int r = idx - 2 * FEAT * FEAT;
            int n = r >> 7, k = r & 127;
            ((unsigned short*)WoutT)[r] = bf16_rn(Wout[k * OUTF + n]);
        }
        return;
    }

    // ---- per-(bucket,replica) histogram ----
    __shared__ int h[8192];
    int nb8 = NB * NREP;
    for (int i = t; i < nb8; i += 256) h[i] = 0;
    __syncthreads();
    int stride = NHIST * 256;
    for (int e = bid * 256 + t; e < E; e += stride) {
        int rep = (e >> SCHUNK_SH) & (NREP - 1);
        atomicAdd(&h[((dst[e] >> BSH) << 3) | rep], 1);
    }
    __syncthreads();
    for (int i = t; i < nb8; i += 256)
        if (h[i]) atomicAdd(&bcnt8[i], h[i]);

    // ---- decoupled: last histogram block performs the scan ----
    __shared__ int amLast;
    __threadfence();
    __syncthreads();
    if (t == 0) amLast = (atomicAdd(done, 1) == NHIST - 1);
    __syncthreads();
    if (!amLast) return;
    __threadfence();

    // exclusive scan of bcnt8[nb8] -> bcur8 (absolute), bbase
    int per = 32;                         // nb8 <= 8192 = 256*32
    int base = t * per;
    int v[32];
    int local = 0;
    #pragma unroll
    for (int i = 0; i < 32; ++i) {
        int g = base + i;
        v[i] = (g < nb8) ? bcnt8[g] : 0;
        local += v[i];
    }
    int lane = t & 63, wv = t >> 6;
    int x = local;
    #pragma unroll
    for (int o = 1; o < 64; o <<= 1) {
        int y = __shfl_up(x, o);
        if (lane >= o) x += y;
    }
    __shared__ int wsum[4];
    if (lane == 63) wsum[wv] = x;
    __syncthreads();
    int woff = 0;
    for (int i = 0; i < wv; ++i) woff += wsum[i];
    int run = woff + x - local;
    #pragma unroll
    for (int i = 0; i < 32; ++i) {
        int g = base + i;
        if (g < nb8) {
            bcur8[g] = run;
            if ((g & (NREP - 1)) == 0) bbase[g >> 3] = run;
        }
        run += v[i];
    }
    if (t == 0) bbase[NB] = E;
}

// ---- bin_scatter: two-phase, dst cached in LDS ----
__global__ __launch_bounds__(256) void bin_scatter_kernel(
        const int* __restrict__ src, const int* __restrict__ dst,
        int* __restrict__ bcur8, unsigned int* __restrict__ staged,
        int E, int NB) {
    __shared__ int lcnt[1024];
    __shared__ int lbase[1024];
    __shared__ int dstb[SCHUNK];          // 16 KB
    int t = threadIdx.x;
    int rep = blockIdx.x & (NREP - 1);
    int e0 = blockIdx.x << SCHUNK_SH;
    int e1 = min(e0 + SCHUNK, E);
    int len = e1 - e0;
    for (int i = t; i < NB; i += 256) lcnt[i] = 0;
    __syncthreads();
    for (int li = t; li < len; li += 256) {
        int d = dst[e0 + li];
        dstb[li] = d;
        atomicAdd(&lcnt[d >> BSH], 1);
    }
    __syncthreads();
    for (int i = t; i < NB; i += 256) {
        int c = lcnt[i];
        lbase[i] = c ? atomicAdd(&bcur8[(i << 3) | rep], c) : 0;
        lcnt[i] = 0;
    }
    __syncthreads();
    for (int li = t; li < len; li += 256) {
        int s = src[e0 + li], d = dstb[li];
        int b = d >> BSH, dl = d & (BNODES - 1);
        int pos = lbase[b] + atomicAdd(&lcnt[b], 1);
        staged[pos] = (unsigned int)s | ((unsigned int)dl << 25);
    }
}

// ---- bucket_place: segment staged in LDS; row_ptr, dinv, csr_src ----
__global__ __launch_bounds__(256) void bucket_place_kernel(
        const unsigned int* __restrict__ staged, const int* __restrict__ bbase,
        int* __restrict__ row_ptr, float* __restrict__ dinv,
        int* __restrict__ csr_src, int N, int E) {
    int b = blockIdx.x;
    int t = threadIdx.x;
    int base = bbase[b], end = bbase[b + 1];
    int len = end - base;
    __shared__ unsigned int buf[4096];    // 16 KB
    __shared__ int cnt[BNODES];
    __shared__ int cur[BNODES];
    __shared__ int wsum2[2];
    bool fits = len <= 4096;
    if (t < BNODES) cnt[t] = 0;
    __syncthreads();
    if (fits) {
        for (int i = t; i < len; i += 256) {
            unsigned int u = staged[base + i];
            buf[i] = u;
            atomicAdd(&cnt[u >> 25], 1);
        }
    } else {
        for (int i = base + t; i < end; i += 256)
            atomicAdd(&cnt[staged[i] >> 25], 1);
    }
    __syncthreads();

    // exclusive scan of cnt[0..127] using waves 0,1
    bool act = t < BNODES;
    int v = act ? cnt[t] : 0;
    int lane = t & 63, wv = t >> 6;
    int x = v;
    #pragma unroll
    for (int o = 1; o < 64; o <<= 1) {
        int y = __shfl_up(x, o);
        if (lane >= o) x += y;
    }
    if (lane == 63 && wv == 0) wsum2[0] = x;
    __syncthreads();
    if (act) {
        int excl = x - v + (wv == 1 ? wsum2[0] : 0);
        int gnode = b * BNODES + t;
        int rp = base + excl;
        cur[t] = rp;
        if (gnode < N) {
            row_ptr[gnode] = rp;
            dinv[gnode] = rsqrtf((float)v + 1.0f);
        }
    }
    __syncthreads();
    if (fits) {
        for (int i = t; i < len; i += 256) {
            unsigned int u = buf[i];
            int dl = u >> 25;
            int p = atomicAdd(&cur[dl], 1);
            csr_src[p] = (int)(u & 0x1FFFFFFu);
        }
    } else {
        for (int i = base + t; i < end; i += 256) {
            unsigned int u = staged[i];
            int dl = u >> 25;
            int p = atomicAdd(&cur[dl], 1);
            csr_src[p] = (int)(u & 0x1FFFFFFu);
        }
    }
    if (b == 0 && t == 0) row_ptr[N] = E;
}

// ---- MFMA GEMM: Hs[N][128] = bf16( (X[N][128] @ W) * dinv[row] ) ----
template <bool IN_FP32>
__global__ __launch_bounds__(256) void mfma_gemm_kernel(
        const void* __restrict__ Xv, const __hip_bfloat16* __restrict__ Wt,
        const float* __restrict__ dinv, __hip_bfloat16* __restrict__ Y, int N) {
    __shared__ short Ws[FEAT][136];
    int t = threadIdx.x;
    for (int i = t; i < FEAT * 16; i += 256) {
        int n = i >> 4, c = i & 15;
        *(uint4*)&Ws[n][c * 8] = *(const uint4*)((const unsigned short*)Wt + n * FEAT + c * 8);
    }
    __syncthreads();

    int wave = t >> 6, lane = t & 63;
    int m = lane & 15, quad = lane >> 4;
    int rbase = (blockIdx.x * 4 + wave) * 16;
    if (rbase >= N) return;                 // wave-uniform
    int row = rbase + m;
    bool rok = row < N;

    f32x4 acc[8];
    #pragma unroll
    for (int nt = 0; nt < 8; ++nt) acc[nt] = (f32x4){0.f, 0.f, 0.f, 0.f};

    #pragma unroll
    for (int ks = 0; ks < 4; ++ks) {
        short8 a;
        if (IN_FP32) {
            const float* X = (const float*)Xv;
            float xs[8];
            if (rok) {
                float4 x0 = *(const float4*)(X + (size_t)row * FEAT + ks * 32 + quad * 8);
                float4 x1 = *(const float4*)(X + (size_t)row * FEAT + ks * 32 + quad * 8 + 4);
                xs[0] = x0.x; xs[1] = x0.y; xs[2] = x0.z; xs[3] = x0.w;
                xs[4] = x1.x; xs[5] = x1.y; xs[6] = x1.z; xs[7] = x1.w;
            } else {
                #pragma unroll
                for (int j = 0; j < 8; ++j) xs[j] = 0.f;
            }
            #pragma unroll
            for (int j = 0; j < 8; ++j) a[j] = (short)bf16_rn(xs[j]);
        } else {
            const unsigned short* X = (const unsigned short*)Xv;
            if (rok)
                a = *(const short8*)(X + (size_t)row * FEAT + ks * 32 + quad * 8);
            else {
                #pragma unroll
                for (int j = 0; j < 8; ++j) a[j] = 0;
            }
        }
        #pragma unroll
        for (int nt = 0; nt < 8; ++nt) {
            short8 bfr = *(const short8*)&Ws[nt * 16 + m][ks * 32 + quad * 8];
            acc[nt] = __builtin_amdgcn_mfma_f32_16x16x32_bf16(a, bfr, acc[nt], 0, 0, 0);
        }
    }

    float dr[4];
    #pragma unroll
    for (int r = 0; r < 4; ++r) {
        int ro = rbase + quad * 4 + r;
        dr[r] = (ro < N) ? dinv[ro] : 0.f;
    }
    unsigned short* Yo = (unsigned short*)Y;
    #pragma unroll
    for (int nt = 0; nt < 8; ++nt) {
        #pragma unroll
        for (int r = 0; r < 4; ++r) {
            int ro = rbase + quad * 4 + r;
            if (ro < N)
                Yo[(size_t)ro * FEAT + nt * 16 + m] = bf16_rn(acc[nt][r] * dr[r]);
        }
    }
}

// ---- CSR gather (prescaled Hs): A[d] = relu(di*(sum Hs[s] + Hs[d]) + b) ----
__global__ __launch_bounds__(256) void gather_kernel(
        const int* __restrict__ row_ptr, const int* __restrict__ csr_src,
        const float* __restrict__ dinv, const __hip_bfloat16* __restrict__ Hs,
        const float* __restrict__ bias, __hip_bfloat16* __restrict__ A, int N) {
    int node = blockIdx.x * 4 + (threadIdx.x >> 6);
    if (node >= N) return;
    int lane = threadIdx.x & 63;
    const unsigned int* H2 = (const unsigned int*)Hs;
    float ax = 0.f, ay = 0.f;

    int j = row_ptr[node], end = row_ptr[node + 1];
    for (; j + 8 <= end; j += 8) {
        int s0 = csr_src[j + 0], s1 = csr_src[j + 1];
        int s2 = csr_src[j + 2], s3 = csr_src[j + 3];
        int s4 = csr_src[j + 4], s5 = csr_src[j + 5];
        int s6 = csr_src[j + 6], s7 = csr_src[j + 7];
        unsigned int u0 = H2[(size_t)s0 * 64 + lane];
        unsigned int u1 = H2[(size_t)s1 * 64 + lane];
        unsigned int u2 = H2[(size_t)s2 * 64 + lane];
        unsigned int u3 = H2[(size_t)s3 * 64 + lane];
        unsigned int u4 = H2[(size_t)s4 * 64 + lane];
        unsigned int u5 = H2[(size_t)s5 * 64 + lane];
        unsigned int u6 = H2[(size_t)s6 * 64 + lane];
        unsigned int u7 = H2[(size_t)s7 * 64 + lane];
        ax += bf16_lo(u0) + bf16_lo(u1) + bf16_lo(u2) + bf16_lo(u3)
            + bf16_lo(u4) + bf16_lo(u5) + bf16_lo(u6) + bf16_lo(u7);
        ay += bf16_hi(u0) + bf16_hi(u1) + bf16_hi(u2) + bf16_hi(u3)
            + bf16_hi(u4) + bf16_hi(u5) + bf16_hi(u6) + bf16_hi(u7);
    }
    for (; j < end; ++j) {
        int s = csr_src[j];
        unsigned int u = H2[(size_t)s * 64 + lane];
        ax += bf16_lo(u);
        ay += bf16_hi(u);
    }
    unsigned int hu = H2[(size_t)node * 64 + lane];
    ax += bf16_lo(hu);
    ay += bf16_hi(hu);
    float di = dinv[node];
    float2 b2 = ((const float2*)bias)[lane];
    ax = fmaxf(di * ax + b2.x, 0.f);
    ay = fmaxf(di * ay + b2.y, 0.f);
    ((unsigned int*)A)[(size_t)node * 64 + lane] =
        (unsigned int)bf16_rn(ax) | ((unsigned int)bf16_rn(ay) << 16);
}

// ---- final: logits = H@Wout + bout via MFMA ; log_softmax in registers ----
__global__ __launch_bounds__(256) void final_mfma_kernel(
        const __hip_bfloat16* __restrict__ H, const __hip_bfloat16* __restrict__ WoutT,
        const float* __restrict__ bout, float* __restrict__ out, int N) {
    __shared__ short Ws[OUTF][136];
    int t = threadIdx.x;
    for (int i = t; i < OUTF * 16; i += 256) {
        int n = i >> 4, c = i & 15;
        *(uint4*)&Ws[n][c * 8] = *(const uint4*)((const unsigned short*)WoutT + n * FEAT + c * 8);
    }
    __syncthreads();

    int wave = t >> 6, lane = t & 63;
    int m = lane & 15, quad = lane >> 4;
    int rbase = blockIdx.x * 64 + wave * 16;
    if (rbase >= N) return;                 // wave-uniform
    int row = rbase + m;
    bool rok = row < N;

    f32x4 acc[4];
    #pragma unroll
    for (int nt = 0; nt < 4; ++nt) acc[nt] = (f32x4){0.f, 0.f, 0.f, 0.f};

    const unsigned short* Hu = (const unsigned short*)H;
    #pragma unroll
    for (int ks = 0; ks < 4; ++ks) {
        short8 a;
        if (rok)
            a = *(const short8*)(Hu + (size_t)row * FEAT + ks * 32 + quad * 8);
        else {
            #pragma unroll
            for (int j = 0; j < 8; ++j) a[j] = 0;
        }
        #pragma unroll
        for (int nt = 0; nt < 4; ++nt) {
            short8 bfr = *(const short8*)&Ws[nt * 16 + m][ks * 32 + quad * 8];
            acc[nt] = __builtin_amdgcn_mfma_f32_16x16x32_bf16(a, bfr, acc[nt], 0, 0, 0);
        }
    }

    float bj[4];
    #pragma unroll
    for (int nt = 0; nt < 4; ++nt) bj[nt] = bout[nt * 16 + m];

    #pragma unroll
    for (int r = 0; r < 4; ++r) {
        int ro = rbase + quad * 4 + r;
        if (ro >= N) continue;
        float v0 = acc[0][r] + bj[0];
        float v1 = acc[1][r] + bj[1];
        float v2 = acc[2][r] + bj[2];
        float v3 = acc[3][r] + bj[3];
        float mx = fmaxf(fmaxf(v0, v1), fmaxf(v2, v3));
        #pragma unroll
        for (int o = 1; o <= 8; o <<= 1) mx = fmaxf(mx, __shfl_xor(mx, o));
        float s = __expf(v0 - mx) + __expf(v1 - mx) + __expf(v2 - mx) + __expf(v3 - mx);
        #pragma unroll
        for (int o = 1; o <= 8; o <<= 1) s += __shfl_xor(s, o);
        float ls = mx + __logf(s);
        float* op = out + (size_t)ro * OUTF + m;
        op[0]  = v0 - ls;
        op[16] = v1 - ls;
        op[32] = v2 - ls;
        op[48] = v3 - ls;
    }
}

extern "C" void kernel_launch(void* const* d_in, const int* in_sizes, int n_in,
                              void* d_out, int out_size, void* d_ws, size_t ws_size,
                              hipStream_t stream) {
    const float* x    = (const float*)d_in[0];
    const int*   ei   = (const int*)  d_in[1];
    const float* W1   = (const float*)d_in[2];
    const float* b1   = (const float*)d_in[3];
    const float* W2   = (const float*)d_in[4];
    const float* b2   = (const float*)d_in[5];
    const float* Wout = (const float*)d_in[6];
    const float* bout = (const float*)d_in[7];
    float* out = (float*)d_out;

    int N = in_sizes[0] / FEAT;
    int E = in_sizes[1] / 2;
    const int* srcp = ei;
    const int* dstp = ei + E;
    int NB = (N + BNODES - 1) >> BSH;   // <= 1024 for N <= 131072

    char* ws = (char*)d_ws;
    __hip_bfloat16* Bh   = (__hip_bfloat16*)ws;                   // N*128 bf16
    __hip_bfloat16* Ba   = Bh + (size_t)N * FEAT;                 // N*128 bf16
    __hip_bfloat16* W1t  = Ba + (size_t)N * FEAT;                 // 16384 bf16
    __hip_bfloat16* W2t  = W1t + FEAT * FEAT;                     // 16384 bf16
    __hip_bfloat16* WoutT = W2t + FEAT * FEAT;                    // 8192 bf16
    float* dinv    = (float*)(WoutT + OUTF * FEAT);               // N
    int*   rowp    = (int*)(dinv + N);                            // N+1
    int*   bcnt8   = rowp + N + 1;                                // 8192
    int*   done    = bcnt8 + 8192;                                // 1
    int*   bcur8   = done + 1;                                    // 8192
    int*   bbase   = bcur8 + 8192;                                // NB+1
    unsigned int* staged = (unsigned int*)(bbase + 1032);         // E
    int*   csrsrc  = (int*)(staged + E);                          // E

    // zero bcnt8 + done in one memset
    hipMemsetAsync(bcnt8, 0, (size_t)(8192 + 1) * sizeof(int), stream);

    int convw_blocks = (2 * FEAT * FEAT + OUTF * FEAT + 255) / 256;   // 160
    build1_kernel<<<NHIST + convw_blocks, 256, 0, stream>>>(
        dstp, bcnt8, done, bcur8, bbase, E, NB, W1, W2, Wout, W1t, W2t, WoutT);
    bin_scatter_kernel<<<(E + SCHUNK - 1) / SCHUNK, 256, 0, stream>>>(
        srcp, dstp, bcur8, staged, E, NB);
    bucket_place_kernel<<<NB, 256, 0, stream>>>(staged, bbase, rowp, dinv, csrsrc, N, E);

    int ggrid = (N + 63) / 64;
    int agrid = (N + 3) / 4;

    // Layer 1
    mfma_gemm_kernel<true><<<ggrid, 256, 0, stream>>>(x, W1t, dinv, Bh, N);
    gather_kernel<<<agrid, 256, 0, stream>>>(rowp, csrsrc, dinv, Bh, b1, Ba, N);

    // Layer 2
    mfma_gemm_kernel<false><<<ggrid, 256, 0, stream>>>(Ba, W2t, dinv, Bh, N);
    gather_kernel<<<agrid, 256, 0, stream>>>(rowp, csrsrc, dinv, Bh, b2, Ba, N);

    // Output layer (MFMA) + log_softmax
    final_mfma_kernel<<<(N + 63) / 64, 256, 0, stream>>>(Ba, WoutT, bout, out, N);
}